// Round 6
// baseline (70.627 us; speedup 1.0000x reference)
//
#include <hip/hip_runtime.h>

typedef unsigned long long u64;

#define IMG_H 1024
#define IMG_W 1024
#define NIMG  16
#define WPR   16                      // u64 words per image row (1024 bits)
#define MAXD  20
#define HALO  19                      // cov_k (k<=19) reach
#define CORE  26                      // 64 = HALO + CORE + HALO
#define TILES_Y 40                    // ceil(1024/26); cores partition [0,1040)
#define NBLK2 (NIMG * TILES_Y * 2)    // 1280 single-wave blocks
#define PBLK  2048                    // blocks for pack_kernel

typedef float f4 __attribute__((ext_vector_type(4)));
typedef int   i4 __attribute__((ext_vector_type(4)));

template <typename T>
__device__ __forceinline__ T ntload(const T* p) {
    return __builtin_nontemporal_load(p);
}

// -------- Kernel 1: binarize + bit-pack, barrier-free, nt loads -------------
// Each thread owns two groups of 16 contiguous px; per-lane u16 masks stored
// directly to global (4 adjacent u16 little-endian == the output u64 word).
// 16 independent 16B loads in flight per thread, no LDS, no ballots.

__global__ __launch_bounds__(256) void pack_kernel(
    const float* __restrict__ pred, const int* __restrict__ targ,
    unsigned short* __restrict__ hp, unsigned short* __restrict__ ht)
{
    const int tid = blockIdx.x * 256 + threadIdx.x;   // 0 .. 524287
    const int nth = PBLK * 256;                       // 524288 = ngroups/2

    const f4* p0 = reinterpret_cast<const f4*>(pred + (long long)tid * 16);
    const i4* t0 = reinterpret_cast<const i4*>(targ + (long long)tid * 16);
    const f4* p1 = reinterpret_cast<const f4*>(pred + ((long long)tid + nth) * 16);
    const i4* t1 = reinterpret_cast<const i4*>(targ + ((long long)tid + nth) * 16);

    f4 P0[4], P1[4];
    i4 T0[4], T1[4];
    #pragma unroll
    for (int n = 0; n < 4; ++n) P0[n] = ntload(p0 + n);
    #pragma unroll
    for (int n = 0; n < 4; ++n) T0[n] = ntload(t0 + n);
    #pragma unroll
    for (int n = 0; n < 4; ++n) P1[n] = ntload(p1 + n);
    #pragma unroll
    for (int n = 0; n < 4; ++n) T1[n] = ntload(t1 + n);

    unsigned int mp0 = 0, mt0 = 0, mp1 = 0, mt1 = 0;
    #pragma unroll
    for (int n = 0; n < 4; ++n) {
        #pragma unroll
        for (int j = 0; j < 4; ++j) {
            const int b = 4 * n + j;
            mp0 |= (P0[n][j] > 0.0f ? 1u : 0u) << b;
            mt0 |= (T0[n][j] != 0   ? 1u : 0u) << b;
            mp1 |= (P1[n][j] > 0.0f ? 1u : 0u) << b;
            mt1 |= (T1[n][j] != 0   ? 1u : 0u) << b;
        }
    }

    hp[tid]       = (unsigned short)mp0;
    ht[tid]       = (unsigned short)mt0;
    hp[tid + nth] = (unsigned short)mp1;
    ht[tid + nth] = (unsigned short)mt1;
}

// -------- Kernel 2: register-resident bit dilation, one row per lane --------
// S_dist = sum_{k=0..19} popcount(C & ~dilate^k(seeds)).
// Single-wave blocks: vertical exchange via shfl, zero barriers.

__device__ inline u64 shfl_up1_u64(u64 x) {
    unsigned int lo = (unsigned int)x, hi = (unsigned int)(x >> 32);
    lo = __shfl_up(lo, 1);
    hi = __shfl_up(hi, 1);
    return ((u64)hi << 32) | (u64)lo;
}
__device__ inline u64 shfl_dn1_u64(u64 x) {
    unsigned int lo = (unsigned int)x, hi = (unsigned int)(x >> 32);
    lo = __shfl_down(lo, 1);
    hi = __shfl_down(hi, 1);
    return ((u64)hi << 32) | (u64)lo;
}

__global__ __launch_bounds__(64) void dt_kernel(
    const u64* __restrict__ gp, const u64* __restrict__ gt,
    uint4* __restrict__ partials)
{
    const int l     = threadIdx.x;
    const int stage = blockIdx.x & 1;
    const int tile  = (blockIdx.x >> 1) % TILES_Y;
    const int img   = blockIdx.x / (2 * TILES_Y);
    const int y0    = tile * CORE;                 // core rows [y0, y0+CORE)
    const int gy    = y0 - HALO + l;               // this lane's row
    const bool inimg = (gy >= 0 && gy < IMG_H);
    const u64 alive  = inimg ? ~0ULL : 0ULL;
    const bool core  = (l >= HALO) && (l < HALO + CORE) && (gy < IMG_H);

    const u64* __restrict__ dil = (stage == 0) ? gp : gt;  // dilated mask
    const u64* __restrict__ oth = (stage == 0) ? gt : gp;  // summed-over mask
    const long long rb = ((long long)img * IMG_H + gy) * WPR;

    u64 s[16], C[16];
    #pragma unroll
    for (int c = 0; c < 16; ++c) {
        s[c] = inimg ? dil[rb + c] : 0ULL;
        C[c] = core  ? oth[rb + c] : 0ULL;   // C==0 off-core => popcounts self-mask
    }

    unsigned int sD = 0, sC = 0;
    #pragma unroll
    for (int c = 0; c < 16; ++c) {           // k = 0 term
        sC += (unsigned int)__popcll(C[c]);
        sD += (unsigned int)__popcll(C[c] & ~s[c]);
    }

    #pragma unroll 1
    for (int k = 1; k < MAXD; ++k) {
        // saturation early-exit: monotone OR; once all in-image rows are
        // all-ones, every remaining round contributes exactly 0.
        u64 andall = ~0ULL;
        #pragma unroll
        for (int c = 0; c < 16; ++c) andall &= s[c];
        if (__all(!inimg || (andall == ~0ULL))) break;

        u64 h[16];
        #pragma unroll
        for (int c = 0; c < 16; ++c)          // in-word horizontal dilate
            h[c] = s[c] | (s[c] << 1) | (s[c] >> 1);
        #pragma unroll
        for (int c = 0; c < 15; ++c) {        // cross-word carries
            h[c]     |= s[c + 1] << 63;
            h[c + 1] |= s[c] >> 63;
        }
        #pragma unroll
        for (int c = 0; c < 16; ++c) {        // vertical OR via shfl, fused popcount
            const u64 up = shfl_up1_u64(h[c]);
            const u64 dn = shfl_dn1_u64(h[c]);
            const u64 v  = (h[c] | up | dn) & alive;
            s[c] = v;
            sD += (unsigned int)__popcll(C[c] & ~v);
        }
    }

    // 64-lane reduce of (sD, sC)
    for (int o = 32; o > 0; o >>= 1) {
        sD += __shfl_down(sD, o);
        sC += __shfl_down(sC, o);
    }
    if (l == 0) {
        partials[blockIdx.x] = (stage == 0) ? make_uint4(sD, sC, 0u, 0u)
                                            : make_uint4(0u, 0u, sD, sC);
    }
}

// -------- Kernel 3: reduce partials + final scalar ---------------------------

__global__ __launch_bounds__(256) void final_kernel(
    const uint4* __restrict__ partials, float* __restrict__ out)
{
    unsigned int s1 = 0, s2 = 0, s3 = 0, s4 = 0;
    for (int i = threadIdx.x; i < NBLK2; i += 256) {
        const uint4 p = partials[i];
        s1 += p.x; s2 += p.y; s3 += p.z; s4 += p.w;
    }
    for (int o = 32; o > 0; o >>= 1) {
        s1 += __shfl_down(s1, o);
        s2 += __shfl_down(s2, o);
        s3 += __shfl_down(s3, o);
        s4 += __shfl_down(s4, o);
    }
    __shared__ uint4 wsum[4];
    const int wid = threadIdx.x >> 6;
    if ((threadIdx.x & 63) == 0) wsum[wid] = make_uint4(s1, s2, s3, s4);
    __syncthreads();
    if (threadIdx.x == 0) {
        uint4 a = wsum[0], b = wsum[1], c = wsum[2], d = wsum[3];
        const float eps = 1e-6f;
        const float S1 = (float)(a.x + b.x + c.x + d.x);
        const float S2 = (float)(a.y + b.y + c.y + d.y);
        const float S3 = (float)(a.z + b.z + c.z + d.z);
        const float S4 = (float)(a.w + b.w + c.w + d.w);
        out[0] = 0.5f * ((S1 + eps) / (S2 + eps) + (S3 + eps) / (S4 + eps));
    }
}

extern "C" void kernel_launch(void* const* d_in, const int* in_sizes, int n_in,
                              void* d_out, int out_size, void* d_ws, size_t ws_size,
                              hipStream_t stream) {
    const float* pred = (const float*)d_in[0];
    const int*   targ = (const int*)d_in[1];
    const size_t nwords = (size_t)NIMG * IMG_H * IMG_W / 64;   // 262,144

    u64*   gp       = (u64*)d_ws;                              // 2 MB
    u64*   gt       = gp + nwords;                             // 2 MB
    uint4* partials = (uint4*)(gt + nwords);                   // 20 KB
    float* out = (float*)d_out;

    pack_kernel<<<PBLK, 256, 0, stream>>>(pred, targ,
                                          (unsigned short*)gp, (unsigned short*)gt);
    dt_kernel<<<NBLK2, 64, 0, stream>>>(gp, gt, partials);
    final_kernel<<<1, 256, 0, stream>>>(partials, out);
}

// Round 7
// 41.619 us; speedup vs baseline: 1.6970x; 1.6970x over previous
//
#include <hip/hip_runtime.h>

typedef unsigned long long u64;

#define IMG_H 1024
#define IMG_W 1024
#define NIMG  16
#define WPR   16                      // u64 words per image row (1024 bits)
#define MAXD  20
#define HALO  19                      // cov_k (k<=19) reach
#define CORE  26                      // 64 = HALO + CORE + HALO
#define TILES_Y 40                    // ceil(1024/26); cores partition [0,1040)
#define NBLK2 (NIMG * TILES_Y * 2)    // 1280 single-wave blocks
#define PBLK  4096                    // blocks for pack_kernel (1 group/thread)

typedef float f4 __attribute__((ext_vector_type(4)));
typedef int   i4 __attribute__((ext_vector_type(4)));

// -------- Kernel 1: binarize + bit-pack, sc0 (L1-bypass, L2/L3-allocate) ----
// Each thread owns 16 contiguous px; per-lane u16 masks stored directly to
// global (4 adjacent u16 little-endian == the output u64 word).

__global__ __launch_bounds__(256) void pack_kernel(
    const float* __restrict__ pred, const int* __restrict__ targ,
    unsigned short* __restrict__ hp, unsigned short* __restrict__ ht)
{
    const int tid = blockIdx.x * 256 + threadIdx.x;   // 0 .. 1048575
    const f4* pp = reinterpret_cast<const f4*>(pred) + (long long)tid * 4;
    const i4* tp = reinterpret_cast<const i4*>(targ) + (long long)tid * 4;

    f4 P0, P1, P2, P3;
    i4 T0, T1, T2, T3;
    // Issue all 8 loads with sc0 (bypass L1, keep L2/MALL), then one wait that
    // ties the results (compiler cannot hoist uses past it).
    asm volatile("global_load_dwordx4 %0, %1, off sc0" : "=&v"(P0) : "v"(pp + 0));
    asm volatile("global_load_dwordx4 %0, %1, off sc0" : "=&v"(P1) : "v"(pp + 1));
    asm volatile("global_load_dwordx4 %0, %1, off sc0" : "=&v"(P2) : "v"(pp + 2));
    asm volatile("global_load_dwordx4 %0, %1, off sc0" : "=&v"(P3) : "v"(pp + 3));
    asm volatile("global_load_dwordx4 %0, %1, off sc0" : "=&v"(T0) : "v"(tp + 0));
    asm volatile("global_load_dwordx4 %0, %1, off sc0" : "=&v"(T1) : "v"(tp + 1));
    asm volatile("global_load_dwordx4 %0, %1, off sc0" : "=&v"(T2) : "v"(tp + 2));
    asm volatile("global_load_dwordx4 %0, %1, off sc0" : "=&v"(T3) : "v"(tp + 3));
    asm volatile("s_waitcnt vmcnt(0)"
                 : "+v"(P0), "+v"(P1), "+v"(P2), "+v"(P3),
                   "+v"(T0), "+v"(T1), "+v"(T2), "+v"(T3));

    unsigned int mp = 0, mt = 0;
    #pragma unroll
    for (int j = 0; j < 4; ++j) {
        mp |= (P0[j] > 0.0f ? 1u : 0u) << j;
        mp |= (P1[j] > 0.0f ? 1u : 0u) << (4 + j);
        mp |= (P2[j] > 0.0f ? 1u : 0u) << (8 + j);
        mp |= (P3[j] > 0.0f ? 1u : 0u) << (12 + j);
        mt |= (T0[j] != 0 ? 1u : 0u) << j;
        mt |= (T1[j] != 0 ? 1u : 0u) << (4 + j);
        mt |= (T2[j] != 0 ? 1u : 0u) << (8 + j);
        mt |= (T3[j] != 0 ? 1u : 0u) << (12 + j);
    }

    hp[tid] = (unsigned short)mp;
    ht[tid] = (unsigned short)mt;
}

// -------- Kernel 2: register-resident bit dilation, one row per lane --------
// S_dist = sum_{k=0..19} popcount(C & ~dilate^k(seeds)).
// Single-wave blocks: vertical exchange via shfl, zero barriers.

__device__ inline u64 shfl_up1_u64(u64 x) {
    unsigned int lo = (unsigned int)x, hi = (unsigned int)(x >> 32);
    lo = __shfl_up(lo, 1);
    hi = __shfl_up(hi, 1);
    return ((u64)hi << 32) | (u64)lo;
}
__device__ inline u64 shfl_dn1_u64(u64 x) {
    unsigned int lo = (unsigned int)x, hi = (unsigned int)(x >> 32);
    lo = __shfl_down(lo, 1);
    hi = __shfl_down(hi, 1);
    return ((u64)hi << 32) | (u64)lo;
}

__global__ __launch_bounds__(64) void dt_kernel(
    const u64* __restrict__ gp, const u64* __restrict__ gt,
    uint4* __restrict__ partials)
{
    const int l     = threadIdx.x;
    const int stage = blockIdx.x & 1;
    const int tile  = (blockIdx.x >> 1) % TILES_Y;
    const int img   = blockIdx.x / (2 * TILES_Y);
    const int y0    = tile * CORE;                 // core rows [y0, y0+CORE)
    const int gy    = y0 - HALO + l;               // this lane's row
    const bool inimg = (gy >= 0 && gy < IMG_H);
    const u64 alive  = inimg ? ~0ULL : 0ULL;
    const bool core  = (l >= HALO) && (l < HALO + CORE) && (gy < IMG_H);

    const u64* __restrict__ dil = (stage == 0) ? gp : gt;  // dilated mask
    const u64* __restrict__ oth = (stage == 0) ? gt : gp;  // summed-over mask
    const long long rb = ((long long)img * IMG_H + gy) * WPR;

    u64 s[16], C[16];
    #pragma unroll
    for (int c = 0; c < 16; ++c) {
        s[c] = inimg ? dil[rb + c] : 0ULL;
        C[c] = core  ? oth[rb + c] : 0ULL;   // C==0 off-core => popcounts self-mask
    }

    unsigned int sD = 0, sC = 0;
    #pragma unroll
    for (int c = 0; c < 16; ++c) {           // k = 0 term
        sC += (unsigned int)__popcll(C[c]);
        sD += (unsigned int)__popcll(C[c] & ~s[c]);
    }

    #pragma unroll 1
    for (int k = 1; k < MAXD; ++k) {
        // saturation early-exit: monotone OR; once all in-image rows are
        // all-ones, every remaining round contributes exactly 0.
        u64 andall = ~0ULL;
        #pragma unroll
        for (int c = 0; c < 16; ++c) andall &= s[c];
        if (__all(!inimg || (andall == ~0ULL))) break;

        u64 h[16];
        #pragma unroll
        for (int c = 0; c < 16; ++c)          // in-word horizontal dilate
            h[c] = s[c] | (s[c] << 1) | (s[c] >> 1);
        #pragma unroll
        for (int c = 0; c < 15; ++c) {        // cross-word carries
            h[c]     |= s[c + 1] << 63;
            h[c + 1] |= s[c] >> 63;
        }
        #pragma unroll
        for (int c = 0; c < 16; ++c) {        // vertical OR via shfl, fused popcount
            const u64 up = shfl_up1_u64(h[c]);
            const u64 dn = shfl_dn1_u64(h[c]);
            const u64 v  = (h[c] | up | dn) & alive;
            s[c] = v;
            sD += (unsigned int)__popcll(C[c] & ~v);
        }
    }

    // 64-lane reduce of (sD, sC)
    for (int o = 32; o > 0; o >>= 1) {
        sD += __shfl_down(sD, o);
        sC += __shfl_down(sC, o);
    }
    if (l == 0) {
        partials[blockIdx.x] = (stage == 0) ? make_uint4(sD, sC, 0u, 0u)
                                            : make_uint4(0u, 0u, sD, sC);
    }
}

// -------- Kernel 3: reduce partials + final scalar ---------------------------

__global__ __launch_bounds__(256) void final_kernel(
    const uint4* __restrict__ partials, float* __restrict__ out)
{
    unsigned int s1 = 0, s2 = 0, s3 = 0, s4 = 0;
    for (int i = threadIdx.x; i < NBLK2; i += 256) {
        const uint4 p = partials[i];
        s1 += p.x; s2 += p.y; s3 += p.z; s4 += p.w;
    }
    for (int o = 32; o > 0; o >>= 1) {
        s1 += __shfl_down(s1, o);
        s2 += __shfl_down(s2, o);
        s3 += __shfl_down(s3, o);
        s4 += __shfl_down(s4, o);
    }
    __shared__ uint4 wsum[4];
    const int wid = threadIdx.x >> 6;
    if ((threadIdx.x & 63) == 0) wsum[wid] = make_uint4(s1, s2, s3, s4);
    __syncthreads();
    if (threadIdx.x == 0) {
        uint4 a = wsum[0], b = wsum[1], c = wsum[2], d = wsum[3];
        const float eps = 1e-6f;
        const float S1 = (float)(a.x + b.x + c.x + d.x);
        const float S2 = (float)(a.y + b.y + c.y + d.y);
        const float S3 = (float)(a.z + b.z + c.z + d.z);
        const float S4 = (float)(a.w + b.w + c.w + d.w);
        out[0] = 0.5f * ((S1 + eps) / (S2 + eps) + (S3 + eps) / (S4 + eps));
    }
}

extern "C" void kernel_launch(void* const* d_in, const int* in_sizes, int n_in,
                              void* d_out, int out_size, void* d_ws, size_t ws_size,
                              hipStream_t stream) {
    const float* pred = (const float*)d_in[0];
    const int*   targ = (const int*)d_in[1];
    const size_t nwords = (size_t)NIMG * IMG_H * IMG_W / 64;   // 262,144

    u64*   gp       = (u64*)d_ws;                              // 2 MB
    u64*   gt       = gp + nwords;                             // 2 MB
    uint4* partials = (uint4*)(gt + nwords);                   // 20 KB
    float* out = (float*)d_out;

    pack_kernel<<<PBLK, 256, 0, stream>>>(pred, targ,
                                          (unsigned short*)gp, (unsigned short*)gt);
    dt_kernel<<<NBLK2, 64, 0, stream>>>(gp, gt, partials);
    final_kernel<<<1, 256, 0, stream>>>(partials, out);
}